// Round 5
// baseline (113022.693 us; speedup 1.0000x reference)
//
#include <hip/hip_runtime.h>
#include <math.h>

#define BB 32
#define TENC 200
#define NMELS 80
#define TMELS 400
#define STEPS 200
#define MEM 256
#define PRE1N 256
#define PRE2N 128
#define AD 128
#define DK 21
#define DF 8
#define SK 21
#define SF 8
#define PL 11

// workspace offsets (floats)
#define WS_W640   0u           // [640][1024]  LSTM1: k=[ctx256,pre128,h1 256]
#define WS_W768   655360u      // [768][1024]  LSTM2: k=[h1 256,ctx256,h2 256]
#define WS_ATTWT  1441792u     // [256][128]
#define WS_ATTVT  1474560u     // [128][168]
#define WS_PW1T   1496064u     // [80][256]
#define WS_PW2T   1516544u     // [256][128]
#define WS_PRE2   1549312u     // [200][32][128]
#define WS_ALIGN  2368512u     // [32][200]
#define WS_CTX2   2374912u     // [2][32][256]
#define WS_H1     2391296u     // [2][32][256]
#define WS_C1     2407680u     // [32][256]
#define WS_H2     2415872u     // [2][32][256]
#define WS_C2     2432256u     // [32][256]
#define WS_FBUF   2440448u     // [32][8][200]
#define WS_PBUF   2491648u     // [32][200]
// total 2,498,048 floats = 9.99 MB
#define SLOT 8192u             // 32*256

__device__ __forceinline__ float sigm(float x){ return 1.f/(1.f+expf(-x)); }

__global__ __launch_bounds__(256) void trk(const float* __restrict__ s, float* __restrict__ d, int R, int C){
  int i = blockIdx.x*256 + threadIdx.x;
  if (i < R*C){ int r = i / C, c = i - r*C; d[c*R + r] = s[i]; }
}

__global__ __launch_bounds__(256) void initk(float* __restrict__ ws){
  int b = blockIdx.x, tid = threadIdx.x;
  for (int i=tid;i<TENC;i+=256) ws[WS_ALIGN + b*TENC + i] = (i==0)?1.f:0.f;
  ws[WS_CTX2 + b*256u + tid]=0.f; ws[WS_CTX2 + SLOT + b*256u + tid]=0.f;
  ws[WS_H1   + b*256u + tid]=0.f; ws[WS_H1   + SLOT + b*256u + tid]=0.f;
  ws[WS_H2   + b*256u + tid]=0.f; ws[WS_H2   + SLOT + b*256u + tid]=0.f;
  ws[WS_C1   + b*256u + tid]=0.f; ws[WS_C2   + b*256u + tid]=0.f;
}

// prenet for all 200 steps: block = one timestep, 32 batch rows
__global__ __launch_bounds__(256) void prenetk(const float* __restrict__ mels,
    const float* __restrict__ b1, const float* __restrict__ b2, float* __restrict__ ws){
  int t = blockIdx.x, tid = threadIdx.x;
  __shared__ float xS[BB*NMELS];
  __shared__ float p1S[BB*PRE1N];
  const float* W1T = ws + WS_PW1T;
  const float* W2T = ws + WS_PW2T;
  for (int i=tid;i<BB*NMELS;i+=256){
    int r = i/NMELS, k = i - r*NMELS;
    xS[i] = (t==0)?0.f : mels[r*NMELS*TMELS + k*TMELS + (2*t-1)];
  }
  __syncthreads();
  {
    float acc[BB];
    #pragma unroll
    for (int r=0;r<BB;r++) acc[r]=0.f;
    for (int k=0;k<NMELS;k++){
      float w = W1T[k*PRE1N + tid];
      #pragma unroll
      for (int r=0;r<BB;r++) acc[r] += xS[r*NMELS+k]*w;
    }
    float bb = b1[tid];
    #pragma unroll
    for (int r=0;r<BB;r++) p1S[r*PRE1N+tid] = fmaxf(acc[r]+bb, 0.f);
  }
  __syncthreads();
  if (tid < PRE2N){
    float acc[BB];
    #pragma unroll
    for (int r=0;r<BB;r++) acc[r]=0.f;
    for (int k=0;k<PRE1N;k++){
      float w = W2T[k*PRE2N + tid];
      #pragma unroll
      for (int r=0;r<BB;r++) acc[r] += p1S[r*PRE1N+k]*w;
    }
    float bb = b2[tid];
    #pragma unroll
    for (int r=0;r<BB;r++) ws[WS_PRE2 + ((unsigned)t*BB + r)*PRE2N + tid] = fmaxf(acc[r]+bb, 0.f);
  }
}

// Launch A(t):
//  blocks 0..31 : LSTM1 step t (out-split: block j owns neurons [8j,8j+8), all 32 batches)   [t<200]
//  blocks 32..63: LSTM2 step t-1 (same structure, K=768)                                     [t>=1]
//  blocks 64..71: prior conv + static conv on align_{t-1} (4 batches per block)              [t<200]
__global__ __launch_bounds__(256) void stepA(
    const float* __restrict__ albih, const float* __restrict__ albhh,
    const float* __restrict__ dlbih, const float* __restrict__ dlbhh,
    const float* __restrict__ prior, const float* __restrict__ attF,
    float* __restrict__ ws, int t){
  int blk = blockIdx.x, tid = threadIdx.x;
  __shared__ float actS[32*132];
  __shared__ float wS[32*132];
  __shared__ float wFS[SF*SK];
  __shared__ float prS[PL];
  __shared__ float alS[4*TENC];
  const int wp = t & 1, rp = wp ^ 1;

  if (blk < 32){
    if (t >= STEPS) return;
    const int n_loc = tid & 7, b = tid >> 3;
    const int nn = 8*blk + n_loc;
    float acc0 = albih[nn]      + albhh[nn];
    float acc1 = albih[256+nn]  + albhh[256+nn];
    float acc2 = albih[512+nn]  + albhh[512+nn];
    float acc3 = albih[768+nn]  + albhh[768+nn];
    const float* W = ws + WS_W640;
    for (int ch = 0; ch < 5; ch++){
      const int k0 = ch*128;
      const float* src; int bstr;
      if (ch < 2)      { src = ws + WS_CTX2 + rp*SLOT + k0;        bstr = 256; }
      else if (ch == 2){ src = ws + WS_PRE2 + (unsigned)t*4096u;   bstr = 128; }
      else             { src = ws + WS_H1   + rp*SLOT + (k0-384);  bstr = 256; }
      for (int idx = tid; idx < 4096; idx += 256){
        int bb = idx >> 7, kl = idx & 127;
        actS[bb*132 + kl] = src[bb*bstr + kl];
      }
      for (int idx = tid; idx < 4096; idx += 256){
        int c = idx & 31, kl = idx >> 5;
        int col = 256*(c>>3) + 8*blk + (c&7);
        wS[c*132 + kl] = W[(unsigned)(k0+kl)*1024u + col];
      }
      __syncthreads();
      const float* aR = actS + b*132;
      const float* w0 = wS + (0*8+n_loc)*132;
      const float* w1 = wS + (1*8+n_loc)*132;
      const float* w2 = wS + (2*8+n_loc)*132;
      const float* w3 = wS + (3*8+n_loc)*132;
      for (int kl = 0; kl < 128; kl += 4){
        float4 a4 = *(const float4*)(aR + kl);
        float4 x0 = *(const float4*)(w0 + kl);
        float4 x1 = *(const float4*)(w1 + kl);
        float4 x2 = *(const float4*)(w2 + kl);
        float4 x3 = *(const float4*)(w3 + kl);
        acc0 += a4.x*x0.x + a4.y*x0.y + a4.z*x0.z + a4.w*x0.w;
        acc1 += a4.x*x1.x + a4.y*x1.y + a4.z*x1.z + a4.w*x1.w;
        acc2 += a4.x*x2.x + a4.y*x2.y + a4.z*x2.z + a4.w*x2.w;
        acc3 += a4.x*x3.x + a4.y*x3.y + a4.z*x3.z + a4.w*x3.w;
      }
      __syncthreads();
    }
    float c_old = ws[WS_C1 + b*256u + nn];
    float cn = sigm(acc1)*c_old + sigm(acc0)*tanhf(acc2);
    float hn = sigm(acc3)*tanhf(cn);
    ws[WS_C1 + b*256u + nn] = cn;
    ws[WS_H1 + wp*SLOT + b*256u + nn] = hn;
  } else if (blk < 64){
    if (t < 1) return;
    const int j2 = blk - 32;
    const int n_loc = tid & 7, b = tid >> 3;
    const int nn = 8*j2 + n_loc;
    float acc0 = dlbih[nn]      + dlbhh[nn];
    float acc1 = dlbih[256+nn]  + dlbhh[256+nn];
    float acc2 = dlbih[512+nn]  + dlbhh[512+nn];
    float acc3 = dlbih[768+nn]  + dlbhh[768+nn];
    const float* W = ws + WS_W768;
    for (int ch = 0; ch < 6; ch++){
      const int k0 = ch*128;
      const float* src;
      if (ch < 2)      src = ws + WS_H1   + rp*SLOT + k0;
      else if (ch < 4) src = ws + WS_CTX2 + rp*SLOT + (k0-256);
      else             src = ws + WS_H2   + wp*SLOT + (k0-512);
      for (int idx = tid; idx < 4096; idx += 256){
        int bb = idx >> 7, kl = idx & 127;
        actS[bb*132 + kl] = src[bb*256 + kl];
      }
      for (int idx = tid; idx < 4096; idx += 256){
        int c = idx & 31, kl = idx >> 5;
        int col = 256*(c>>3) + 8*j2 + (c&7);
        wS[c*132 + kl] = W[(unsigned)(k0+kl)*1024u + col];
      }
      __syncthreads();
      const float* aR = actS + b*132;
      const float* w0 = wS + (0*8+n_loc)*132;
      const float* w1 = wS + (1*8+n_loc)*132;
      const float* w2 = wS + (2*8+n_loc)*132;
      const float* w3 = wS + (3*8+n_loc)*132;
      for (int kl = 0; kl < 128; kl += 4){
        float4 a4 = *(const float4*)(aR + kl);
        float4 x0 = *(const float4*)(w0 + kl);
        float4 x1 = *(const float4*)(w1 + kl);
        float4 x2 = *(const float4*)(w2 + kl);
        float4 x3 = *(const float4*)(w3 + kl);
        acc0 += a4.x*x0.x + a4.y*x0.y + a4.z*x0.z + a4.w*x0.w;
        acc1 += a4.x*x1.x + a4.y*x1.y + a4.z*x1.z + a4.w*x1.w;
        acc2 += a4.x*x2.x + a4.y*x2.y + a4.z*x2.z + a4.w*x2.w;
        acc3 += a4.x*x3.x + a4.y*x3.y + a4.z*x3.z + a4.w*x3.w;
      }
      __syncthreads();
    }
    float c_old = ws[WS_C2 + b*256u + nn];
    float cn = sigm(acc1)*c_old + sigm(acc0)*tanhf(acc2);
    float hn = sigm(acc3)*tanhf(cn);
    ws[WS_C2 + b*256u + nn] = cn;
    ws[WS_H2 + rp*SLOT + b*256u + nn] = hn;   // h2_{t-1} -> slot (t-1)&1
  } else {
    if (t >= STEPS) return;
    const int j3 = blk - 64;
    if (tid < SF*SK) wFS[tid] = attF[tid];
    if (tid < PL)    prS[tid] = prior[tid];
    const int bg = tid >> 6, lane = tid & 63;
    const int b = j3*4 + bg;
    for (int pos = lane; pos < TENC; pos += 64) alS[bg*TENC+pos] = ws[WS_ALIGN + b*TENC + pos];
    __syncthreads();
    for (int pos = lane; pos < TENC; pos += 64){
      float s = 0.f;
      #pragma unroll
      for (int jj = 0; jj < PL; jj++){ int q = pos - jj; if (q >= 0) s += prS[jj]*alS[bg*TENC+q]; }
      ws[WS_PBUF + b*TENC + pos] = logf(fmaxf(s, 1e-6f));
    }
    for (int it = lane; it < SF*TENC; it += 64){
      int chn = it / TENC, pos = it - chn*TENC;
      float s = 0.f;
      #pragma unroll
      for (int k = 0; k < SK; k++){ int q = pos + k - 10; if (q>=0 && q<TENC) s += wFS[chn*SK+k]*alS[bg*TENC+q]; }
      ws[WS_FBUF + b*SF*TENC + it] = s;
    }
  }
}

// Launch B(t):
//  blocks 0..31 : DCA for step t (per-batch): q,G,e,softmax -> align_t, ctx_t   [t<200]
//  blocks 32..36: acoustic projection for step t-1 (out-split, 32 cols/block)   [t>=1]
__global__ __launch_bounds__(1024) void stepB(
    const float* __restrict__ attWb, const float* __restrict__ attU,
    const float* __restrict__ attT, const float* __restrict__ attTb,
    const float* __restrict__ attv, const float* __restrict__ memory,
    const float* __restrict__ acW, const float* __restrict__ acb,
    float* __restrict__ ws, float* __restrict__ out, int t){
  int blk = blockIdx.x, tid = threadIdx.x;
  const int wp = t & 1, rp = wp ^ 1;
  __shared__ float h1S[256], qS[AD], GS[DF*DK], ctxS[256];
  __shared__ float alS[TENC], fS[SF*TENC], pS[TENC], eS[TENC];
  __shared__ float part[1024];
  __shared__ float rb[17];
  __shared__ float uS[AD*SF], tS2[AD*DF], tbS[AD], vS[AD];
  __shared__ float actP[32*260];

  if (blk < 32){
    if (t >= STEPS) return;
    const int b = blk;
    if (tid < 256) h1S[tid] = ws[WS_H1 + wp*SLOT + b*256u + tid];
    for (int i=tid;i<TENC;i+=1024){ alS[i] = ws[WS_ALIGN + b*TENC + i]; pS[i] = ws[WS_PBUF + b*TENC + i]; }
    for (int i=tid;i<SF*TENC;i+=1024) fS[i] = ws[WS_FBUF + b*SF*TENC + i];
    for (int i=tid;i<AD*SF;i+=1024) uS[i]  = attU[i];
    for (int i=tid;i<AD*DF;i+=1024) tS2[i] = attT[i];
    if (tid < AD){ tbS[tid] = attTb[tid]; vS[tid] = attv[tid]; }
    __syncthreads();
    // q = tanh(attW @ h1 + Wb): 512 threads, 4 k-quarters
    if (tid < 512){
      const int quarter = tid >> 7, a = tid & 127;
      const float* attWT = ws + WS_ATTWT;
      float s = 0.f;
      for (int k = 64*quarter; k < 64*quarter+64; k++) s += h1S[k]*attWT[k*AD + a];
      part[tid] = s;
    }
    __syncthreads();
    if (tid < AD) qS[tid] = tanhf(attWb[tid] + part[tid] + part[128+tid] + part[256+tid] + part[384+tid]);
    __syncthreads();
    // G = attV @ q
    if (tid < DF*DK){
      const float* attVT = ws + WS_ATTVT;
      float a = 0.f;
      for (int k = 0; k < AD; k++) a += qS[k]*attVT[k*(DF*DK) + tid];
      GS[tid] = a;
    }
    __syncthreads();
    // e[pos] = v . tanh(U f + T g + Tb) + p
    if (tid < 4*TENC){
      const int pos = tid >> 2, qr = tid & 3;
      float g[DF];
      #pragma unroll
      for (int c=0;c<DF;c++){
        float s=0.f;
        #pragma unroll
        for (int k=0;k<DK;k++){
          int q2 = pos + k - 10;
          if (q2>=0 && q2<TENC) s += alS[q2]*GS[c*DK+k];
        }
        g[c]=s;
      }
      float pp = 0.f;
      for (int h = qr*32; h < qr*32+32; h++){
        float u = tbS[h];
        #pragma unroll
        for (int s2=0;s2<SF;s2++) u += uS[h*SF+s2]*fS[s2*TENC+pos];
        #pragma unroll
        for (int c=0;c<DF;c++) u += tS2[h*DF+c]*g[c];
        pp += vS[h]*tanhf(u);
      }
      pp += __shfl_xor(pp,1);
      pp += __shfl_xor(pp,2);
      if (qr==0) eS[pos] = pp + pS[pos];
    }
    __syncthreads();
    // softmax over 200
    float ex;
    {
      float v = (tid<TENC)? eS[tid] : -3.0e38f;
      for (int o=1;o<64;o<<=1) v = fmaxf(v, __shfl_xor(v,o));
      if ((tid&63)==0) rb[tid>>6] = v;
      __syncthreads();
      if (tid==0){ float m=rb[0]; for(int w=1;w<16;w++) m=fmaxf(m,rb[w]); rb[16]=m; }
      __syncthreads();
      float m = rb[16];
      ex = (tid<TENC)? expf(eS[tid]-m) : 0.f;
      float sv = ex;
      for (int o=1;o<64;o<<=1) sv += __shfl_xor(sv,o);
      __syncthreads();
      if ((tid&63)==0) rb[tid>>6] = sv;
      __syncthreads();
      if (tid==0){ float s=0.f; for(int w=0;w<16;w++) s+=rb[w]; rb[16]=1.f/s; }
      __syncthreads();
      float inv = rb[16];
      if (tid<TENC){
        float a = ex*inv;
        alS[tid] = a;
        ws[WS_ALIGN + b*TENC + tid] = a;
        out[1024000 + b*TENC*STEPS + tid*STEPS + t] = a;
      }
    }
    __syncthreads();
    // ctx = align @ memory[b]
    {
      int grp = tid >> 8, j = tid & 255;
      float a=0.f;
      for (int p=grp*50; p<grp*50+50; p++) a += alS[p]*memory[(b*TENC+p)*MEM + j];
      part[grp*256+j] = a;
    }
    __syncthreads();
    if (tid < 256){
      float c = part[tid]+part[256+tid]+part[512+tid]+part[768+tid];
      ctxS[tid]=c;
      ws[WS_CTX2 + wp*SLOT + b*256u + tid] = c;
    }
  } else {
    if (t < 1) return;
    // projection for step t-1: acc over K=512 [h2_{t-1}, ctx_{t-1}]
    const int p = blk - 32;
    const int b = tid >> 5, col_loc = tid & 31;
    const int col = 32*p + col_loc;
    float acc = 0.f;
    for (int ch = 0; ch < 2; ch++){
      const float* src = (ch==0) ? (ws + WS_H2 + rp*SLOT) : (ws + WS_CTX2 + rp*SLOT);
      for (int idx = tid; idx < 32*256; idx += 1024){
        int bb = idx >> 8, kl = idx & 255;
        actP[bb*260 + kl] = src[bb*256 + kl];
      }
      __syncthreads();
      const float* aR = actP + b*260;
      const float* wR = acW + col*512 + ch*256;
      for (int kl = 0; kl < 256; kl += 4){
        float4 a4 = *(const float4*)(aR + kl);
        float4 w4 = *(const float4*)(wR + kl);
        acc += a4.x*w4.x + a4.y*w4.y + a4.z*w4.z + a4.w*w4.w;
      }
      __syncthreads();
    }
    acc += acb[col];
    const int m = col >> 1, r = col & 1;
    out[(unsigned)b*NMELS*TMELS + m*TMELS + 2*(t-1) + r] = acc;
  }
}

extern "C" void kernel_launch(void* const* d_in, const int* in_sizes, int n_in,
                              void* d_out, int out_size, void* d_ws, size_t ws_size,
                              hipStream_t stream) {
  (void)in_sizes; (void)n_in; (void)out_size; (void)ws_size;
  const float* mels   = (const float*)d_in[0];
  const float* memory = (const float*)d_in[1];
  const float* pre_W1 = (const float*)d_in[2];
  const float* pre_b1 = (const float*)d_in[3];
  const float* pre_W2 = (const float*)d_in[4];
  const float* pre_b2 = (const float*)d_in[5];
  const float* al_Wih = (const float*)d_in[6];
  const float* al_Whh = (const float*)d_in[7];
  const float* al_bih = (const float*)d_in[8];
  const float* al_bhh = (const float*)d_in[9];
  const float* att_W  = (const float*)d_in[10];
  const float* att_Wb = (const float*)d_in[11];
  const float* att_V  = (const float*)d_in[12];
  const float* att_F  = (const float*)d_in[13];
  const float* att_U  = (const float*)d_in[14];
  const float* att_T  = (const float*)d_in[15];
  const float* att_Tb = (const float*)d_in[16];
  const float* att_v  = (const float*)d_in[17];
  const float* prior  = (const float*)d_in[18];
  const float* dl_Wih = (const float*)d_in[19];
  const float* dl_Whh = (const float*)d_in[20];
  const float* dl_bih = (const float*)d_in[21];
  const float* dl_bhh = (const float*)d_in[22];
  const float* ac_W   = (const float*)d_in[23];
  const float* ac_b   = (const float*)d_in[24];
  float* ws  = (float*)d_ws;
  float* out = (float*)d_out;

  auto TR = [&](const float* src, unsigned off, int R, int C){
    int n = R*C;
    trk<<<dim3((n+255)/256), dim3(256), 0, stream>>>(src, ws + off, R, C);
  };
  TR(al_Wih, WS_W640,              1024, 384);
  TR(al_Whh, WS_W640 + 384u*1024u, 1024, 256);
  TR(dl_Wih, WS_W768,              1024, 512);
  TR(dl_Whh, WS_W768 + 512u*1024u, 1024, 256);
  TR(att_W,  WS_ATTWT, 128, 256);
  TR(att_V,  WS_ATTVT, 168, 128);
  TR(pre_W1, WS_PW1T,  256, 80);
  TR(pre_W2, WS_PW2T,  128, 256);

  initk<<<dim3(BB), dim3(256), 0, stream>>>(ws);
  prenetk<<<dim3(STEPS), dim3(256), 0, stream>>>(mels, pre_b1, pre_b2, ws);

  for (int t = 0; t <= STEPS; t++){
    stepA<<<dim3(72), dim3(256), 0, stream>>>(al_bih, al_bhh, dl_bih, dl_bhh, prior, att_F, ws, t);
    stepB<<<dim3(37), dim3(1024), 0, stream>>>(att_Wb, att_U, att_T, att_Tb, att_v,
                                               memory, ac_W, ac_b, ws, out, t);
  }
}

// Round 6
// 85872.382 us; speedup vs baseline: 1.3162x; 1.3162x over previous
//
#include <hip/hip_runtime.h>
#include <math.h>

#define BB 32
#define TENC 200
#define NMELS 80
#define TMELS 400
#define STEPS 200
#define MEM 256
#define PRE1N 256
#define PRE2N 128
#define AD 128
#define DK 21
#define DF 8
#define SK 21
#define SF 8
#define PL 11

// workspace offsets (floats)
#define WS_W640   0u           // [640][1024]  LSTM1: k=[ctx256,pre128,h1 256]
#define WS_W768   655360u      // [768][1024]  LSTM2: k=[h1 256,ctx256,h2 256]
#define WS_ATTWT  1441792u     // [256][128]
#define WS_ATTVT  1474560u     // [128][168]
#define WS_PW1T   1496064u     // [80][256]
#define WS_PW2T   1516544u     // [256][128]
#define WS_PRE2   1549312u     // [200][32][128]
#define WS_ALIGN  2368512u     // [32][200]
#define WS_CTX2   2374912u     // [2][32][256]
#define WS_H1     2391296u     // [2][32][256]
#define WS_C1     2407680u     // [32][256]
#define WS_H2     2415872u     // [2][32][256]
#define WS_C2     2432256u     // [32][256]
#define WS_FBUF   2440448u     // [32][8][200]
#define WS_PBUF   2491648u     // [32][200]
#define WS_BAR    2498048u     // 640 floats barrier state
// total 2,498,688 floats ~= 10.0 MB
#define SLOT 8192u             // 32*256
#define G_NBLK 72

__device__ __forceinline__ float sigm(float x){ return 1.f/(1.f+expf(-x)); }
__device__ __forceinline__ float tanh_fast(float x){
  float ax = fabsf(x);
  float z = __expf(-2.f*ax);
  float r = (1.f - z)/(1.f + z);
  return (x < 0.f) ? -r : r;
}

// two-level grid barrier: 9 groups of 8 blocks -> top(9) -> generation bump.
// agent-scope atomics give cross-XCD release/acquire; generation scheme avoids reset races.
__device__ __forceinline__ void gridbar(unsigned* B, int blk){
  __syncthreads();
  if (threadIdx.x == 0){
    unsigned* gc  = B + (blk >> 3) * 32;   // per-group counter, 128B apart
    unsigned* top = B + 512;               // group-count counter
    unsigned* gen = B + 544;               // generation
    unsigned gv = __hip_atomic_load(gen, __ATOMIC_RELAXED, __HIP_MEMORY_SCOPE_AGENT);
    unsigned a  = __hip_atomic_fetch_add(gc, 1u, __ATOMIC_ACQ_REL, __HIP_MEMORY_SCOPE_AGENT);
    if (a == 7u){
      __hip_atomic_store(gc, 0u, __ATOMIC_RELAXED, __HIP_MEMORY_SCOPE_AGENT);
      unsigned b2 = __hip_atomic_fetch_add(top, 1u, __ATOMIC_ACQ_REL, __HIP_MEMORY_SCOPE_AGENT);
      if (b2 == 8u){
        __hip_atomic_store(top, 0u, __ATOMIC_RELAXED, __HIP_MEMORY_SCOPE_AGENT);
        __hip_atomic_fetch_add(gen, 1u, __ATOMIC_RELEASE, __HIP_MEMORY_SCOPE_AGENT);
      } else {
        while (__hip_atomic_load(gen, __ATOMIC_ACQUIRE, __HIP_MEMORY_SCOPE_AGENT) == gv)
          __builtin_amdgcn_s_sleep(1);
      }
    } else {
      while (__hip_atomic_load(gen, __ATOMIC_ACQUIRE, __HIP_MEMORY_SCOPE_AGENT) == gv)
        __builtin_amdgcn_s_sleep(1);
    }
  }
  __syncthreads();
}

__global__ __launch_bounds__(256) void trk(const float* __restrict__ s, float* __restrict__ d, int R, int C){
  int i = blockIdx.x*256 + threadIdx.x;
  if (i < R*C){ int r = i / C, c = i - r*C; d[c*R + r] = s[i]; }
}

__global__ __launch_bounds__(256) void initk(float* __restrict__ ws){
  int b = blockIdx.x, tid = threadIdx.x;
  for (int i=tid;i<TENC;i+=256) ws[WS_ALIGN + b*TENC + i] = (i==0)?1.f:0.f;
  ws[WS_CTX2 + b*256u + tid]=0.f; ws[WS_CTX2 + SLOT + b*256u + tid]=0.f;
  ws[WS_H1   + b*256u + tid]=0.f; ws[WS_H1   + SLOT + b*256u + tid]=0.f;
  ws[WS_H2   + b*256u + tid]=0.f; ws[WS_H2   + SLOT + b*256u + tid]=0.f;
  ws[WS_C1   + b*256u + tid]=0.f; ws[WS_C2   + b*256u + tid]=0.f;
  if (b == 0){ for (int i=tid;i<640;i+=256) ws[WS_BAR + i] = 0.f; }
}

// prenet for all 200 steps: block = one timestep, 32 batch rows
__global__ __launch_bounds__(256) void prenetk(const float* __restrict__ mels,
    const float* __restrict__ b1, const float* __restrict__ b2, float* __restrict__ ws){
  int t = blockIdx.x, tid = threadIdx.x;
  __shared__ float xS[BB*NMELS];
  __shared__ float p1S[BB*PRE1N];
  const float* W1T = ws + WS_PW1T;
  const float* W2T = ws + WS_PW2T;
  for (int i=tid;i<BB*NMELS;i+=256){
    int r = i/NMELS, k = i - r*NMELS;
    xS[i] = (t==0)?0.f : mels[r*NMELS*TMELS + k*TMELS + (2*t-1)];
  }
  __syncthreads();
  {
    float acc[BB];
    #pragma unroll
    for (int r=0;r<BB;r++) acc[r]=0.f;
    for (int k=0;k<NMELS;k++){
      float w = W1T[k*PRE1N + tid];
      #pragma unroll
      for (int r=0;r<BB;r++) acc[r] += xS[r*NMELS+k]*w;
    }
    float bb = b1[tid];
    #pragma unroll
    for (int r=0;r<BB;r++) p1S[r*PRE1N+tid] = fmaxf(acc[r]+bb, 0.f);
  }
  __syncthreads();
  if (tid < PRE2N){
    float acc[BB];
    #pragma unroll
    for (int r=0;r<BB;r++) acc[r]=0.f;
    for (int k=0;k<PRE1N;k++){
      float w = W2T[k*PRE2N + tid];
      #pragma unroll
      for (int r=0;r<BB;r++) acc[r] += p1S[r*PRE1N+k]*w;
    }
    float bb = b2[tid];
    #pragma unroll
    for (int r=0;r<BB;r++) ws[WS_PRE2 + ((unsigned)t*BB + r)*PRE2N + tid] = fmaxf(acc[r]+bb, 0.f);
  }
}

// persistent recurrence kernel: 72 blocks x 256 threads, 201 iterations x 2 phases.
// phase A(t): blk 0-31 LSTM1(t) [t<200]; blk 32-63 LSTM2(t-1) [t>=1]; blk 64-71 convs(t) [t<200]
// phase B(t): blk 0-31 DCA(t)   [t<200]; blk 32-41 proj(t-1)  [t>=1]
__global__ __launch_bounds__(256) void persist(
    const float* __restrict__ albih, const float* __restrict__ albhh,
    const float* __restrict__ dlbih, const float* __restrict__ dlbhh,
    const float* __restrict__ prior, const float* __restrict__ attF,
    const float* __restrict__ attWb, const float* __restrict__ attU,
    const float* __restrict__ attT, const float* __restrict__ attTb,
    const float* __restrict__ attv, const float* __restrict__ memory,
    const float* __restrict__ acW, const float* __restrict__ acb,
    float* __restrict__ ws, float* __restrict__ out){
  const int blk = blockIdx.x, tid = threadIdx.x;
  __shared__ float sm[9728];
  unsigned* bar = (unsigned*)(ws + WS_BAR);

  for (int t = 0; t <= STEPS; ++t){
    const int wp = t & 1, rp = wp ^ 1;
    // ================= PHASE A =================
    if (blk < 32){
      if (t < STEPS){
        float* actS = sm;            // [32*132]
        float* wSm  = sm + 4224;     // [32*132]
        const int n_loc = tid & 7, b = tid >> 3;
        const int nn = 8*blk + n_loc;
        float acc0 = albih[nn]      + albhh[nn];
        float acc1 = albih[256+nn]  + albhh[256+nn];
        float acc2 = albih[512+nn]  + albhh[512+nn];
        float acc3 = albih[768+nn]  + albhh[768+nn];
        const float* W = ws + WS_W640;
        for (int ch = 0; ch < 5; ch++){
          const int k0 = ch*128;
          const float* src; int bstr;
          if (ch < 2)      { src = ws + WS_CTX2 + rp*SLOT + k0;        bstr = 256; }
          else if (ch == 2){ src = ws + WS_PRE2 + (unsigned)t*4096u;   bstr = 128; }
          else             { src = ws + WS_H1   + rp*SLOT + (k0-384);  bstr = 256; }
          for (int idx = tid; idx < 4096; idx += 256){
            int bb = idx >> 7, kl = idx & 127;
            actS[bb*132 + kl] = src[bb*bstr + kl];
          }
          for (int idx = tid; idx < 4096; idx += 256){
            int c = idx & 31, kl = idx >> 5;
            int col = 256*(c>>3) + 8*blk + (c&7);
            wSm[c*132 + kl] = W[(unsigned)(k0+kl)*1024u + col];
          }
          __syncthreads();
          const float* aR = actS + b*132;
          const float* w0 = wSm + (0*8+n_loc)*132;
          const float* w1 = wSm + (1*8+n_loc)*132;
          const float* w2 = wSm + (2*8+n_loc)*132;
          const float* w3 = wSm + (3*8+n_loc)*132;
          for (int kl = 0; kl < 128; kl += 4){
            float4 a4 = *(const float4*)(aR + kl);
            float4 x0 = *(const float4*)(w0 + kl);
            float4 x1 = *(const float4*)(w1 + kl);
            float4 x2 = *(const float4*)(w2 + kl);
            float4 x3 = *(const float4*)(w3 + kl);
            acc0 += a4.x*x0.x + a4.y*x0.y + a4.z*x0.z + a4.w*x0.w;
            acc1 += a4.x*x1.x + a4.y*x1.y + a4.z*x1.z + a4.w*x1.w;
            acc2 += a4.x*x2.x + a4.y*x2.y + a4.z*x2.z + a4.w*x2.w;
            acc3 += a4.x*x3.x + a4.y*x3.y + a4.z*x3.z + a4.w*x3.w;
          }
          __syncthreads();
        }
        float c_old = ws[WS_C1 + b*256u + nn];
        float cn = sigm(acc1)*c_old + sigm(acc0)*tanhf(acc2);
        float hn = sigm(acc3)*tanhf(cn);
        ws[WS_C1 + b*256u + nn] = cn;
        ws[WS_H1 + wp*SLOT + b*256u + nn] = hn;
      }
    } else if (blk < 64){
      if (t >= 1){
        float* actS = sm;
        float* wSm  = sm + 4224;
        const int j2 = blk - 32;
        const int n_loc = tid & 7, b = tid >> 3;
        const int nn = 8*j2 + n_loc;
        float acc0 = dlbih[nn]      + dlbhh[nn];
        float acc1 = dlbih[256+nn]  + dlbhh[256+nn];
        float acc2 = dlbih[512+nn]  + dlbhh[512+nn];
        float acc3 = dlbih[768+nn]  + dlbhh[768+nn];
        const float* W = ws + WS_W768;
        for (int ch = 0; ch < 6; ch++){
          const int k0 = ch*128;
          const float* src;
          if (ch < 2)      src = ws + WS_H1   + rp*SLOT + k0;
          else if (ch < 4) src = ws + WS_CTX2 + rp*SLOT + (k0-256);
          else             src = ws + WS_H2   + wp*SLOT + (k0-512);
          for (int idx = tid; idx < 4096; idx += 256){
            int bb = idx >> 7, kl = idx & 127;
            actS[bb*132 + kl] = src[bb*256 + kl];
          }
          for (int idx = tid; idx < 4096; idx += 256){
            int c = idx & 31, kl = idx >> 5;
            int col = 256*(c>>3) + 8*j2 + (c&7);
            wSm[c*132 + kl] = W[(unsigned)(k0+kl)*1024u + col];
          }
          __syncthreads();
          const float* aR = actS + b*132;
          const float* w0 = wSm + (0*8+n_loc)*132;
          const float* w1 = wSm + (1*8+n_loc)*132;
          const float* w2 = wSm + (2*8+n_loc)*132;
          const float* w3 = wSm + (3*8+n_loc)*132;
          for (int kl = 0; kl < 128; kl += 4){
            float4 a4 = *(const float4*)(aR + kl);
            float4 x0 = *(const float4*)(w0 + kl);
            float4 x1 = *(const float4*)(w1 + kl);
            float4 x2 = *(const float4*)(w2 + kl);
            float4 x3 = *(const float4*)(w3 + kl);
            acc0 += a4.x*x0.x + a4.y*x0.y + a4.z*x0.z + a4.w*x0.w;
            acc1 += a4.x*x1.x + a4.y*x1.y + a4.z*x1.z + a4.w*x1.w;
            acc2 += a4.x*x2.x + a4.y*x2.y + a4.z*x2.z + a4.w*x2.w;
            acc3 += a4.x*x3.x + a4.y*x3.y + a4.z*x3.z + a4.w*x3.w;
          }
          __syncthreads();
        }
        float c_old = ws[WS_C2 + b*256u + nn];
        float cn = sigm(acc1)*c_old + sigm(acc0)*tanhf(acc2);
        float hn = sigm(acc3)*tanhf(cn);
        ws[WS_C2 + b*256u + nn] = cn;
        ws[WS_H2 + rp*SLOT + b*256u + nn] = hn;   // h2_{t-1} -> slot (t-1)&1
      }
    } else {
      if (t < STEPS){
        float* wFS  = sm;          // 168
        float* prS  = sm + 192;    // 11
        float* alS4 = sm + 256;    // 800
        const int j3 = blk - 64;
        if (tid < SF*SK) wFS[tid] = attF[tid];
        if (tid < PL)    prS[tid] = prior[tid];
        const int bg = tid >> 6, lane = tid & 63;
        const int b = j3*4 + bg;
        for (int pos = lane; pos < TENC; pos += 64) alS4[bg*TENC+pos] = ws[WS_ALIGN + b*TENC + pos];
        __syncthreads();
        for (int pos = lane; pos < TENC; pos += 64){
          float s = 0.f;
          #pragma unroll
          for (int jj = 0; jj < PL; jj++){ int q = pos - jj; if (q >= 0) s += prS[jj]*alS4[bg*TENC+q]; }
          ws[WS_PBUF + b*TENC + pos] = logf(fmaxf(s, 1e-6f));
        }
        for (int it = lane; it < SF*TENC; it += 64){
          int chn = it / TENC, pos = it - chn*TENC;
          float s = 0.f;
          #pragma unroll
          for (int k = 0; k < SK; k++){ int q = pos + k - 10; if (q>=0 && q<TENC) s += wFS[chn*SK+k]*alS4[bg*TENC+q]; }
          ws[WS_FBUF + b*SF*TENC + it] = s;
        }
      }
    }
    gridbar(bar, blk);
    // ================= PHASE B =================
    if (blk < 32){
      if (t < STEPS){
        const int b = blk;
        float* h1S = sm;           // 256
        float* qS  = sm + 256;     // 128
        float* GS  = sm + 384;     // 168
        float* alS = sm + 552;     // 200
        float* pS  = sm + 752;     // 200
        float* eS  = sm + 952;     // 200
        float* rb  = sm + 1152;    // 8
        float* fS  = sm + 1216;    // 1600
        float* uS  = sm + 2816;    // 1024
        float* tS2 = sm + 3840;    // 1024
        float* tbS = sm + 4864;    // 128
        float* vS  = sm + 4992;    // 128
        h1S[tid] = ws[WS_H1 + wp*SLOT + b*256u + tid];
        for (int i=tid;i<TENC;i+=256){ alS[i] = ws[WS_ALIGN + b*TENC + i]; pS[i] = ws[WS_PBUF + b*TENC + i]; }
        for (int i=tid;i<SF*TENC;i+=256) fS[i] = ws[WS_FBUF + b*SF*TENC + i];
        for (int i=tid;i<AD*SF;i+=256) uS[i]  = attU[i];
        for (int i=tid;i<AD*DF;i+=256) tS2[i] = attT[i];
        if (tid < AD){ tbS[tid] = attTb[tid]; vS[tid] = attv[tid]; }
        __syncthreads();
        if (tid < AD){
          const float* attWT = ws + WS_ATTWT;
          float a = attWb[tid];
          for (int k=0;k<256;k++) a += h1S[k]*attWT[k*AD+tid];
          qS[tid] = tanhf(a);
        }
        __syncthreads();
        if (tid < DF*DK){
          const float* attVT = ws + WS_ATTVT;
          float a = 0.f;
          for (int k=0;k<AD;k++) a += qS[k]*attVT[k*(DF*DK) + tid];
          GS[tid] = a;
        }
        __syncthreads();
        if (tid < TENC){
          const int pos = tid;
          float g[DF];
          #pragma unroll
          for (int c=0;c<DF;c++){
            float s=0.f;
            #pragma unroll
            for (int k=0;k<DK;k++){
              int q2 = pos + k - 10;
              if (q2>=0 && q2<TENC) s += alS[q2]*GS[c*DK+k];
            }
            g[c]=s;
          }
          float pp = 0.f;
          for (int h = 0; h < AD; h++){
            float u = tbS[h];
            #pragma unroll
            for (int s2=0;s2<SF;s2++) u += uS[h*SF+s2]*fS[s2*TENC+pos];
            #pragma unroll
            for (int c=0;c<DF;c++) u += tS2[h*DF+c]*g[c];
            pp += vS[h]*tanh_fast(u);
          }
          eS[pos] = pp + pS[pos];
        }
        __syncthreads();
        // softmax over 200, 4 waves
        float ex;
        {
          float v = (tid<TENC)? eS[tid] : -3.0e38f;
          for (int o=1;o<64;o<<=1) v = fmaxf(v, __shfl_xor(v,o));
          if ((tid&63)==0) rb[tid>>6] = v;
          __syncthreads();
          if (tid==0){ rb[4] = fmaxf(fmaxf(rb[0],rb[1]), fmaxf(rb[2],rb[3])); }
          __syncthreads();
          float m = rb[4];
          ex = (tid<TENC)? expf(eS[tid]-m) : 0.f;
          float sv = ex;
          for (int o=1;o<64;o<<=1) sv += __shfl_xor(sv,o);
          __syncthreads();
          if ((tid&63)==0) rb[tid>>6] = sv;
          __syncthreads();
          if (tid==0){ rb[5] = 1.f/(rb[0]+rb[1]+rb[2]+rb[3]); }
          __syncthreads();
          float inv = rb[5];
          if (tid<TENC){
            float a = ex*inv;
            alS[tid] = a;
            ws[WS_ALIGN + b*TENC + tid] = a;
            out[1024000 + b*TENC*STEPS + tid*STEPS + t] = a;
          }
        }
        __syncthreads();
        // ctx[j=tid] = sum_p align[p] * memory[b][p][j]
        {
          float a0=0.f,a1=0.f,a2=0.f,a3=0.f;
          const float* mb = memory + (unsigned)b*TENC*MEM + tid;
          for (int p=0;p<TENC;p+=4){
            a0 += alS[p  ]*mb[(p  )*MEM];
            a1 += alS[p+1]*mb[(p+1)*MEM];
            a2 += alS[p+2]*mb[(p+2)*MEM];
            a3 += alS[p+3]*mb[(p+3)*MEM];
          }
          ws[WS_CTX2 + wp*SLOT + b*256u + tid] = (a0+a1)+(a2+a3);
        }
      }
    } else if (blk < 42){
      if (t >= 1){
        const int p = blk - 32;
        const int cp = p*256 + tid;          // 0..2559
        const int b = cp / 80;
        const int cpair = cp - b*80;
        const int col0 = 2*cpair;
        const float* h2p = ws + WS_H2   + rp*SLOT + b*256u;
        const float* cxp = ws + WS_CTX2 + rp*SLOT + b*256u;
        const float* w0 = acW + (unsigned)col0*512u;
        const float* w1 = w0 + 512;
        float a0 = acb[col0], a1 = acb[col0+1];
        for (int k=0;k<256;k+=4){
          float4 h4 = *(const float4*)(h2p+k);
          float4 x0 = *(const float4*)(w0+k);
          float4 x1 = *(const float4*)(w1+k);
          a0 += h4.x*x0.x + h4.y*x0.y + h4.z*x0.z + h4.w*x0.w;
          a1 += h4.x*x1.x + h4.y*x1.y + h4.z*x1.z + h4.w*x1.w;
        }
        for (int k=0;k<256;k+=4){
          float4 c4 = *(const float4*)(cxp+k);
          float4 x0 = *(const float4*)(w0+256+k);
          float4 x1 = *(const float4*)(w1+256+k);
          a0 += c4.x*x0.x + c4.y*x0.y + c4.z*x0.z + c4.w*x0.w;
          a1 += c4.x*x1.x + c4.y*x1.y + c4.z*x1.z + c4.w*x1.w;
        }
        const int m0 = cpair;
        out[(unsigned)b*NMELS*TMELS + m0*TMELS + 2*(t-1)    ] = a0;
        out[(unsigned)b*NMELS*TMELS + m0*TMELS + 2*(t-1) + 1] = a1;
      }
    }
    gridbar(bar, blk);
  }
}

extern "C" void kernel_launch(void* const* d_in, const int* in_sizes, int n_in,
                              void* d_out, int out_size, void* d_ws, size_t ws_size,
                              hipStream_t stream) {
  (void)in_sizes; (void)n_in; (void)out_size; (void)ws_size;
  const float* mels   = (const float*)d_in[0];
  const float* memory = (const float*)d_in[1];
  const float* pre_W1 = (const float*)d_in[2];
  const float* pre_b1 = (const float*)d_in[3];
  const float* pre_W2 = (const float*)d_in[4];
  const float* pre_b2 = (const float*)d_in[5];
  const float* al_Wih = (const float*)d_in[6];
  const float* al_Whh = (const float*)d_in[7];
  const float* al_bih = (const float*)d_in[8];
  const float* al_bhh = (const float*)d_in[9];
  const float* att_W  = (const float*)d_in[10];
  const float* att_Wb = (const float*)d_in[11];
  const float* att_V  = (const float*)d_in[12];
  const float* att_F  = (const float*)d_in[13];
  const float* att_U  = (const float*)d_in[14];
  const float* att_T  = (const float*)d_in[15];
  const float* att_Tb = (const float*)d_in[16];
  const float* att_v  = (const float*)d_in[17];
  const float* prior  = (const float*)d_in[18];
  const float* dl_Wih = (const float*)d_in[19];
  const float* dl_Whh = (const float*)d_in[20];
  const float* dl_bih = (const float*)d_in[21];
  const float* dl_bhh = (const float*)d_in[22];
  const float* ac_W   = (const float*)d_in[23];
  const float* ac_b   = (const float*)d_in[24];
  float* ws  = (float*)d_ws;
  float* out = (float*)d_out;

  auto TR = [&](const float* src, unsigned off, int R, int C){
    int n = R*C;
    trk<<<dim3((n+255)/256), dim3(256), 0, stream>>>(src, ws + off, R, C);
  };
  TR(al_Wih, WS_W640,              1024, 384);
  TR(al_Whh, WS_W640 + 384u*1024u, 1024, 256);
  TR(dl_Wih, WS_W768,              1024, 512);
  TR(dl_Whh, WS_W768 + 512u*1024u, 1024, 256);
  TR(att_W,  WS_ATTWT, 128, 256);
  TR(att_V,  WS_ATTVT, 168, 128);
  TR(pre_W1, WS_PW1T,  256, 80);
  TR(pre_W2, WS_PW2T,  128, 256);

  initk<<<dim3(BB), dim3(256), 0, stream>>>(ws);
  prenetk<<<dim3(STEPS), dim3(256), 0, stream>>>(mels, pre_b1, pre_b2, ws);

  persist<<<dim3(G_NBLK), dim3(256), 0, stream>>>(
      al_bih, al_bhh, dl_bih, dl_bhh, prior, att_F,
      att_Wb, att_U, att_T, att_Tb, att_v, memory,
      ac_W, ac_b, ws, out);
}

// Round 7
// 79749.109 us; speedup vs baseline: 1.4172x; 1.0768x over previous
//
#include <hip/hip_runtime.h>
#include <math.h>

#define BB 32
#define TENC 200
#define NMELS 80
#define TMELS 400
#define STEPS 200
#define MEM 256
#define PRE1N 256
#define PRE2N 128
#define AD 128
#define DK 21
#define DF 8
#define SK 21
#define SF 8
#define PL 11

// workspace offsets (floats)
#define WS_W640   0u           // [640][1024]  LSTM1: k=[ctx256,pre128,h1 256]
#define WS_W768   655360u      // [768][1024]  LSTM2: k=[h1 256,ctx256,h2 256]
#define WS_ATTWT  1441792u     // [256][128]
#define WS_ATTVT  1474560u     // [128][168]
#define WS_PW1T   1496064u     // [80][256]
#define WS_PW2T   1516544u     // [256][128]
#define WS_PRE2   1549312u     // [200][32][128]
#define WS_ALIGN  2368512u     // [32][200]
#define WS_CTX2   2374912u     // [2][32][256]
#define WS_H1     2391296u     // [2][32][256]
#define WS_C1     2407680u     // [32][256]
#define WS_H2     2415872u     // [2][32][256]
#define WS_C2     2432256u     // [32][256]
#define WS_FBUF   2440448u     // [32][8][200]
#define WS_PBUF   2491648u     // [32][200]
#define WS_BAR    2498048u     // 640 floats barrier state
// total 2,498,688 floats ~= 10.0 MB
#define SLOT 8192u             // 32*256
#define G_NBLK 72

__device__ __forceinline__ float sigm(float x){ return 1.f/(1.f+expf(-x)); }
__device__ __forceinline__ float tanh_fast(float x){
  float ax = fabsf(x);
  float z = __expf(-2.f*ax);
  float r = (1.f - z)/(1.f + z);
  return (x < 0.f) ? -r : r;
}

// relaxed agent-scope accesses: bypass L1/L2 (coherent at LLC), NO cache invalidates.
__device__ __forceinline__ float ld_cg(const float* p){
  return __hip_atomic_load(p, __ATOMIC_RELAXED, __HIP_MEMORY_SCOPE_AGENT);
}
__device__ __forceinline__ void st_cg(float* p, float v){
  __hip_atomic_store(p, v, __ATOMIC_RELAXED, __HIP_MEMORY_SCOPE_AGENT);
}

// two-level grid barrier, ALL RELAXED + monotone counters (no resets -> no races,
// no acquire/release -> no L2 invalidate storms). `it` = global barrier index.
// Correctness: __syncthreads + vmcnt(0) ensure this block's uncached state stores
// reached the coherent point before its arrival-add; counter RMWs execute at the
// coherent point; waiters re-read state uncached after the generation bump.
__device__ __forceinline__ void gridbar(unsigned* B, int blk, unsigned it){
  __syncthreads();
  if (threadIdx.x == 0){
    unsigned* gc  = B + (blk >> 3) * 32;   // per-group arrival counter (monotone)
    unsigned* top = B + 512;               // group-completion counter (monotone)
    unsigned* gen = B + 544;               // completed-barrier count
    asm volatile("s_waitcnt vmcnt(0)" ::: "memory");
    unsigned a = __hip_atomic_fetch_add(gc, 1u, __ATOMIC_RELAXED, __HIP_MEMORY_SCOPE_AGENT);
    if (a == 8u*it + 7u){
      unsigned b2 = __hip_atomic_fetch_add(top, 1u, __ATOMIC_RELAXED, __HIP_MEMORY_SCOPE_AGENT);
      if (b2 == 9u*it + 8u){
        __hip_atomic_fetch_add(gen, 1u, __ATOMIC_RELAXED, __HIP_MEMORY_SCOPE_AGENT);
      } else {
        while (__hip_atomic_load(gen, __ATOMIC_RELAXED, __HIP_MEMORY_SCOPE_AGENT) <= it)
          __builtin_amdgcn_s_sleep(2);
      }
    } else {
      while (__hip_atomic_load(gen, __ATOMIC_RELAXED, __HIP_MEMORY_SCOPE_AGENT) <= it)
        __builtin_amdgcn_s_sleep(2);
    }
  }
  __syncthreads();
}

__global__ __launch_bounds__(256) void trk(const float* __restrict__ s, float* __restrict__ d, int R, int C){
  int i = blockIdx.x*256 + threadIdx.x;
  if (i < R*C){ int r = i / C, c = i - r*C; d[c*R + r] = s[i]; }
}

__global__ __launch_bounds__(256) void initk(float* __restrict__ ws){
  int b = blockIdx.x, tid = threadIdx.x;
  for (int i=tid;i<TENC;i+=256) ws[WS_ALIGN + b*TENC + i] = (i==0)?1.f:0.f;
  ws[WS_CTX2 + b*256u + tid]=0.f; ws[WS_CTX2 + SLOT + b*256u + tid]=0.f;
  ws[WS_H1   + b*256u + tid]=0.f; ws[WS_H1   + SLOT + b*256u + tid]=0.f;
  ws[WS_H2   + b*256u + tid]=0.f; ws[WS_H2   + SLOT + b*256u + tid]=0.f;
  ws[WS_C1   + b*256u + tid]=0.f; ws[WS_C2   + b*256u + tid]=0.f;
  if (b == 0){ for (int i=tid;i<640;i+=256) ws[WS_BAR + i] = 0.f; }
}

// prenet for all 200 steps: block = one timestep, 32 batch rows
__global__ __launch_bounds__(256) void prenetk(const float* __restrict__ mels,
    const float* __restrict__ b1, const float* __restrict__ b2, float* __restrict__ ws){
  int t = blockIdx.x, tid = threadIdx.x;
  __shared__ float xS[BB*NMELS];
  __shared__ float p1S[BB*PRE1N];
  const float* W1T = ws + WS_PW1T;
  const float* W2T = ws + WS_PW2T;
  for (int i=tid;i<BB*NMELS;i+=256){
    int r = i/NMELS, k = i - r*NMELS;
    xS[i] = (t==0)?0.f : mels[r*NMELS*TMELS + k*TMELS + (2*t-1)];
  }
  __syncthreads();
  {
    float acc[BB];
    #pragma unroll
    for (int r=0;r<BB;r++) acc[r]=0.f;
    for (int k=0;k<NMELS;k++){
      float w = W1T[k*PRE1N + tid];
      #pragma unroll
      for (int r=0;r<BB;r++) acc[r] += xS[r*NMELS+k]*w;
    }
    float bb = b1[tid];
    #pragma unroll
    for (int r=0;r<BB;r++) p1S[r*PRE1N+tid] = fmaxf(acc[r]+bb, 0.f);
  }
  __syncthreads();
  if (tid < PRE2N){
    float acc[BB];
    #pragma unroll
    for (int r=0;r<BB;r++) acc[r]=0.f;
    for (int k=0;k<PRE1N;k++){
      float w = W2T[k*PRE2N + tid];
      #pragma unroll
      for (int r=0;r<BB;r++) acc[r] += p1S[r*PRE1N+k]*w;
    }
    float bb = b2[tid];
    #pragma unroll
    for (int r=0;r<BB;r++) ws[WS_PRE2 + ((unsigned)t*BB + r)*PRE2N + tid] = fmaxf(acc[r]+bb, 0.f);
  }
}

// persistent recurrence kernel: 72 blocks x 256 threads, 201 iterations x 2 phases.
// phase A(t): blk 0-31 LSTM1(t) [t<200]; blk 32-63 LSTM2(t-1) [t>=1]; blk 64-71 convs(t) [t<200]
// phase B(t): blk 0-31 DCA(t)   [t<200]; blk 32-41 proj(t-1)  [t>=1]
__global__ __launch_bounds__(256) void persist(
    const float* __restrict__ albih, const float* __restrict__ albhh,
    const float* __restrict__ dlbih, const float* __restrict__ dlbhh,
    const float* __restrict__ prior, const float* __restrict__ attF,
    const float* __restrict__ attWb, const float* __restrict__ attU,
    const float* __restrict__ attT, const float* __restrict__ attTb,
    const float* __restrict__ attv, const float* __restrict__ memory,
    const float* __restrict__ acW, const float* __restrict__ acb,
    float* __restrict__ ws, float* __restrict__ out){
  const int blk = blockIdx.x, tid = threadIdx.x;
  __shared__ float sm[9728];
  unsigned* bar = (unsigned*)(ws + WS_BAR);
  unsigned bar_it = 0;

  for (int t = 0; t <= STEPS; ++t){
    const int wp = t & 1, rp = wp ^ 1;
    // ================= PHASE A =================
    if (blk < 32){
      if (t < STEPS){
        float* actS = sm;            // [32*132]
        float* wSm  = sm + 4224;     // [32*132]
        const int n_loc = tid & 7, b = tid >> 3;
        const int nn = 8*blk + n_loc;
        float acc0 = albih[nn]      + albhh[nn];
        float acc1 = albih[256+nn]  + albhh[256+nn];
        float acc2 = albih[512+nn]  + albhh[512+nn];
        float acc3 = albih[768+nn]  + albhh[768+nn];
        const float* W = ws + WS_W640;
        for (int ch = 0; ch < 5; ch++){
          const int k0 = ch*128;
          const float* src; int bstr; bool unc;
          if (ch < 2)      { src = ws + WS_CTX2 + rp*SLOT + k0;        bstr = 256; unc = true; }
          else if (ch == 2){ src = ws + WS_PRE2 + (unsigned)t*4096u;   bstr = 128; unc = false; }
          else             { src = ws + WS_H1   + rp*SLOT + (k0-384);  bstr = 256; unc = true; }
          if (unc){
            for (int idx = tid; idx < 4096; idx += 256){
              int bb = idx >> 7, kl = idx & 127;
              actS[bb*132 + kl] = ld_cg(&src[bb*bstr + kl]);
            }
          } else {
            for (int idx = tid; idx < 4096; idx += 256){
              int bb = idx >> 7, kl = idx & 127;
              actS[bb*132 + kl] = src[bb*bstr + kl];
            }
          }
          for (int idx = tid; idx < 4096; idx += 256){
            int c = idx & 31, kl = idx >> 5;
            int col = 256*(c>>3) + 8*blk + (c&7);
            wSm[c*132 + kl] = W[(unsigned)(k0+kl)*1024u + col];
          }
          __syncthreads();
          const float* aR = actS + b*132;
          const float* w0 = wSm + (0*8+n_loc)*132;
          const float* w1 = wSm + (1*8+n_loc)*132;
          const float* w2 = wSm + (2*8+n_loc)*132;
          const float* w3 = wSm + (3*8+n_loc)*132;
          for (int kl = 0; kl < 128; kl += 4){
            float4 a4 = *(const float4*)(aR + kl);
            float4 x0 = *(const float4*)(w0 + kl);
            float4 x1 = *(const float4*)(w1 + kl);
            float4 x2 = *(const float4*)(w2 + kl);
            float4 x3 = *(const float4*)(w3 + kl);
            acc0 += a4.x*x0.x + a4.y*x0.y + a4.z*x0.z + a4.w*x0.w;
            acc1 += a4.x*x1.x + a4.y*x1.y + a4.z*x1.z + a4.w*x1.w;
            acc2 += a4.x*x2.x + a4.y*x2.y + a4.z*x2.z + a4.w*x2.w;
            acc3 += a4.x*x3.x + a4.y*x3.y + a4.z*x3.z + a4.w*x3.w;
          }
          __syncthreads();
        }
        float c_old = ws[WS_C1 + b*256u + nn];
        float cn = sigm(acc1)*c_old + sigm(acc0)*tanhf(acc2);
        float hn = sigm(acc3)*tanhf(cn);
        ws[WS_C1 + b*256u + nn] = cn;
        st_cg(&ws[WS_H1 + wp*SLOT + b*256u + nn], hn);
      }
    } else if (blk < 64){
      if (t >= 1){
        float* actS = sm;
        float* wSm  = sm + 4224;
        const int j2 = blk - 32;
        const int n_loc = tid & 7, b = tid >> 3;
        const int nn = 8*j2 + n_loc;
        float acc0 = dlbih[nn]      + dlbhh[nn];
        float acc1 = dlbih[256+nn]  + dlbhh[256+nn];
        float acc2 = dlbih[512+nn]  + dlbhh[512+nn];
        float acc3 = dlbih[768+nn]  + dlbhh[768+nn];
        const float* W = ws + WS_W768;
        for (int ch = 0; ch < 6; ch++){
          const int k0 = ch*128;
          const float* src;
          if (ch < 2)      src = ws + WS_H1   + rp*SLOT + k0;
          else if (ch < 4) src = ws + WS_CTX2 + rp*SLOT + (k0-256);
          else             src = ws + WS_H2   + wp*SLOT + (k0-512);
          for (int idx = tid; idx < 4096; idx += 256){
            int bb = idx >> 7, kl = idx & 127;
            actS[bb*132 + kl] = ld_cg(&src[bb*256 + kl]);
          }
          for (int idx = tid; idx < 4096; idx += 256){
            int c = idx & 31, kl = idx >> 5;
            int col = 256*(c>>3) + 8*j2 + (c&7);
            wSm[c*132 + kl] = W[(unsigned)(k0+kl)*1024u + col];
          }
          __syncthreads();
          const float* aR = actS + b*132;
          const float* w0 = wSm + (0*8+n_loc)*132;
          const float* w1 = wSm + (1*8+n_loc)*132;
          const float* w2 = wSm + (2*8+n_loc)*132;
          const float* w3 = wSm + (3*8+n_loc)*132;
          for (int kl = 0; kl < 128; kl += 4){
            float4 a4 = *(const float4*)(aR + kl);
            float4 x0 = *(const float4*)(w0 + kl);
            float4 x1 = *(const float4*)(w1 + kl);
            float4 x2 = *(const float4*)(w2 + kl);
            float4 x3 = *(const float4*)(w3 + kl);
            acc0 += a4.x*x0.x + a4.y*x0.y + a4.z*x0.z + a4.w*x0.w;
            acc1 += a4.x*x1.x + a4.y*x1.y + a4.z*x1.z + a4.w*x1.w;
            acc2 += a4.x*x2.x + a4.y*x2.y + a4.z*x2.z + a4.w*x2.w;
            acc3 += a4.x*x3.x + a4.y*x3.y + a4.z*x3.z + a4.w*x3.w;
          }
          __syncthreads();
        }
        float c_old = ws[WS_C2 + b*256u + nn];
        float cn = sigm(acc1)*c_old + sigm(acc0)*tanhf(acc2);
        float hn = sigm(acc3)*tanhf(cn);
        ws[WS_C2 + b*256u + nn] = cn;
        st_cg(&ws[WS_H2 + rp*SLOT + b*256u + nn], hn);   // h2_{t-1} -> slot (t-1)&1
      }
    } else {
      if (t < STEPS){
        float* wFS  = sm;          // 168
        float* prS  = sm + 192;    // 11
        float* alS4 = sm + 256;    // 800
        const int j3 = blk - 64;
        if (tid < SF*SK) wFS[tid] = attF[tid];
        if (tid < PL)    prS[tid] = prior[tid];
        const int bg = tid >> 6, lane = tid & 63;
        const int b = j3*4 + bg;
        for (int pos = lane; pos < TENC; pos += 64) alS4[bg*TENC+pos] = ld_cg(&ws[WS_ALIGN + b*TENC + pos]);
        __syncthreads();
        for (int pos = lane; pos < TENC; pos += 64){
          float s = 0.f;
          #pragma unroll
          for (int jj = 0; jj < PL; jj++){ int q = pos - jj; if (q >= 0) s += prS[jj]*alS4[bg*TENC+q]; }
          st_cg(&ws[WS_PBUF + b*TENC + pos], logf(fmaxf(s, 1e-6f)));
        }
        for (int it = lane; it < SF*TENC; it += 64){
          int chn = it / TENC, pos = it - chn*TENC;
          float s = 0.f;
          #pragma unroll
          for (int k = 0; k < SK; k++){ int q = pos + k - 10; if (q>=0 && q<TENC) s += wFS[chn*SK+k]*alS4[bg*TENC+q]; }
          st_cg(&ws[WS_FBUF + b*SF*TENC + it], s);
        }
      }
    }
    gridbar(bar, blk, bar_it++);
    // ================= PHASE B =================
    if (blk < 32){
      if (t < STEPS){
        const int b = blk;
        float* h1S = sm;           // 256
        float* qS  = sm + 256;     // 128
        float* GS  = sm + 384;     // 168
        float* alS = sm + 552;     // 200
        float* pS  = sm + 752;     // 200
        float* eS  = sm + 952;     // 200
        float* rb  = sm + 1152;    // 8
        float* fS  = sm + 1216;    // 1600
        float* uS  = sm + 2816;    // 1024
        float* tS2 = sm + 3840;    // 1024
        float* tbS = sm + 4864;    // 128
        float* vS  = sm + 4992;    // 128
        h1S[tid] = ld_cg(&ws[WS_H1 + wp*SLOT + b*256u + tid]);
        for (int i=tid;i<TENC;i+=256){ alS[i] = ld_cg(&ws[WS_ALIGN + b*TENC + i]); pS[i] = ld_cg(&ws[WS_PBUF + b*TENC + i]); }
        for (int i=tid;i<SF*TENC;i+=256) fS[i] = ld_cg(&ws[WS_FBUF + b*SF*TENC + i]);
        for (int i=tid;i<AD*SF;i+=256) uS[i]  = attU[i];
        for (int i=tid;i<AD*DF;i+=256) tS2[i] = attT[i];
        if (tid < AD){ tbS[tid] = attTb[tid]; vS[tid] = attv[tid]; }
        __syncthreads();
        if (tid < AD){
          const float* attWT = ws + WS_ATTWT;
          float a = attWb[tid];
          for (int k=0;k<256;k++) a += h1S[k]*attWT[k*AD+tid];
          qS[tid] = tanhf(a);
        }
        __syncthreads();
        if (tid < DF*DK){
          const float* attVT = ws + WS_ATTVT;
          float a = 0.f;
          for (int k=0;k<AD;k++) a += qS[k]*attVT[k*(DF*DK) + tid];
          GS[tid] = a;
        }
        __syncthreads();
        if (tid < TENC){
          const int pos = tid;
          float g[DF];
          #pragma unroll
          for (int c=0;c<DF;c++){
            float s=0.f;
            #pragma unroll
            for (int k=0;k<DK;k++){
              int q2 = pos + k - 10;
              if (q2>=0 && q2<TENC) s += alS[q2]*GS[c*DK+k];
            }
            g[c]=s;
          }
          float pp = 0.f;
          for (int h = 0; h < AD; h++){
            float u = tbS[h];
            #pragma unroll
            for (int s2=0;s2<SF;s2++) u += uS[h*SF+s2]*fS[s2*TENC+pos];
            #pragma unroll
            for (int c=0;c<DF;c++) u += tS2[h*DF+c]*g[c];
            pp += vS[h]*tanh_fast(u);
          }
          eS[pos] = pp + pS[pos];
        }
        __syncthreads();
        // softmax over 200, 4 waves
        float ex;
        {
          float v = (tid<TENC)? eS[tid] : -3.0e38f;
          for (int o=1;o<64;o<<=1) v = fmaxf(v, __shfl_xor(v,o));
          if ((tid&63)==0) rb[tid>>6] = v;
          __syncthreads();
          if (tid==0){ rb[4] = fmaxf(fmaxf(rb[0],rb[1]), fmaxf(rb[2],rb[3])); }
          __syncthreads();
          float m = rb[4];
          ex = (tid<TENC)? expf(eS[tid]-m) : 0.f;
          float sv = ex;
          for (int o=1;o<64;o<<=1) sv += __shfl_xor(sv,o);
          __syncthreads();
          if ((tid&63)==0) rb[tid>>6] = sv;
          __syncthreads();
          if (tid==0){ rb[5] = 1.f/(rb[0]+rb[1]+rb[2]+rb[3]); }
          __syncthreads();
          float inv = rb[5];
          if (tid<TENC){
            float a = ex*inv;
            alS[tid] = a;
            st_cg(&ws[WS_ALIGN + b*TENC + tid], a);
            out[1024000 + b*TENC*STEPS + tid*STEPS + t] = a;
          }
        }
        __syncthreads();
        // ctx[j=tid] = sum_p align[p] * memory[b][p][j]
        {
          float a0=0.f,a1=0.f,a2=0.f,a3=0.f;
          const float* mb = memory + (unsigned)b*TENC*MEM + tid;
          for (int p=0;p<TENC;p+=4){
            a0 += alS[p  ]*mb[(p  )*MEM];
            a1 += alS[p+1]*mb[(p+1)*MEM];
            a2 += alS[p+2]*mb[(p+2)*MEM];
            a3 += alS[p+3]*mb[(p+3)*MEM];
          }
          st_cg(&ws[WS_CTX2 + wp*SLOT + b*256u + tid], (a0+a1)+(a2+a3));
        }
      }
    } else if (blk < 42){
      if (t >= 1){
        const int p = blk - 32;
        const int cp = p*256 + tid;          // 0..2559
        const int b = cp / 80;
        const int cpair = cp - b*80;
        const int col0 = 2*cpair;
        const float* h2p = ws + WS_H2   + rp*SLOT + b*256u;
        const float* cxp = ws + WS_CTX2 + rp*SLOT + b*256u;
        const float* w0 = acW + (unsigned)col0*512u;
        const float* w1 = w0 + 512;
        float a0 = acb[col0], a1 = acb[col0+1];
        for (int k=0;k<256;k++){
          float hv = ld_cg(h2p+k);
          a0 += hv*w0[k]; a1 += hv*w1[k];
        }
        for (int k=0;k<256;k++){
          float cv = ld_cg(cxp+k);
          a0 += cv*w0[256+k]; a1 += cv*w1[256+k];
        }
        const int m0 = cpair;
        out[(unsigned)b*NMELS*TMELS + m0*TMELS + 2*(t-1)    ] = a0;
        out[(unsigned)b*NMELS*TMELS + m0*TMELS + 2*(t-1) + 1] = a1;
      }
    }
    gridbar(bar, blk, bar_it++);
  }
}

extern "C" void kernel_launch(void* const* d_in, const int* in_sizes, int n_in,
                              void* d_out, int out_size, void* d_ws, size_t ws_size,
                              hipStream_t stream) {
  (void)in_sizes; (void)n_in; (void)out_size; (void)ws_size;
  const float* mels   = (const float*)d_in[0];
  const float* memory = (const float*)d_in[1];
  const float* pre_W1 = (const float*)d_in[2];
  const float* pre_b1 = (const float*)d_in[3];
  const float* pre_W2 = (const float*)d_in[4];
  const float* pre_b2 = (const float*)d_in[5];
  const float* al_Wih = (const float*)d_in[6];
  const float* al_Whh = (const float*)d_in[7];
  const float* al_bih = (const float*)d_in[8];
  const float* al_bhh = (const float*)d_in[9];
  const float* att_W  = (const float*)d_in[10];
  const float* att_Wb = (const float*)d_in[11];
  const float* att_V  = (const float*)d_in[12];
  const float* att_F  = (const float*)d_in[13];
  const float* att_U  = (const float*)d_in[14];
  const float* att_T  = (const float*)d_in[15];
  const float* att_Tb = (const float*)d_in[16];
  const float* att_v  = (const float*)d_in[17];
  const float* prior  = (const float*)d_in[18];
  const float* dl_Wih = (const float*)d_in[19];
  const float* dl_Whh = (const float*)d_in[20];
  const float* dl_bih = (const float*)d_in[21];
  const float* dl_bhh = (const float*)d_in[22];
  const float* ac_W   = (const float*)d_in[23];
  const float* ac_b   = (const float*)d_in[24];
  float* ws  = (float*)d_ws;
  float* out = (float*)d_out;

  auto TR = [&](const float* src, unsigned off, int R, int C){
    int n = R*C;
    trk<<<dim3((n+255)/256), dim3(256), 0, stream>>>(src, ws + off, R, C);
  };
  TR(al_Wih, WS_W640,              1024, 384);
  TR(al_Whh, WS_W640 + 384u*1024u, 1024, 256);
  TR(dl_Wih, WS_W768,              1024, 512);
  TR(dl_Whh, WS_W768 + 512u*1024u, 1024, 256);
  TR(att_W,  WS_ATTWT, 128, 256);
  TR(att_V,  WS_ATTVT, 168, 128);
  TR(pre_W1, WS_PW1T,  256, 80);
  TR(pre_W2, WS_PW2T,  128, 256);

  initk<<<dim3(BB), dim3(256), 0, stream>>>(ws);
  prenetk<<<dim3(STEPS), dim3(256), 0, stream>>>(mels, pre_b1, pre_b2, ws);

  persist<<<dim3(G_NBLK), dim3(256), 0, stream>>>(
      al_bih, al_bhh, dl_bih, dl_bhh, prior, att_F,
      att_Wb, att_U, att_T, att_Tb, att_v, memory,
      ac_W, ac_b, ws, out);
}